// Round 2
// baseline (281.418 us; speedup 1.0000x reference)
//
#include <hip/hip_runtime.h>

#define BB 8
#define CC_ALL 64
#define HH 192
#define WW 256
// tile
#define TH 8
#define TW 64
#define CCH 4          // channels per chunk
#define NCHUNK 16      // 64 / 4
#define LDW1 68        // padded stride for x1 tile rows (64 + 4)
#define LDW2 76        // padded stride for x2 halo rows (72 + 4)
#define THREADS 576    // 9 waves, wave w handles i = w - 4

typedef float vfloat4 __attribute__((ext_vector_type(4)));

__global__ __launch_bounds__(THREADS) void cost_volume_kernel(
    const float* __restrict__ x1, const float* __restrict__ x2,
    float* __restrict__ out)
{
    __shared__ __align__(16) float s1[2][CCH * TH * LDW1];        // x1 tile
    __shared__ __align__(16) float s2[2][CCH * (TH + 8) * LDW2];  // x2 halo

    const int tid  = threadIdx.x;
    const int wave = tid >> 6;        // 0..8  -> i = wave - 4
    const int lane = tid & 63;
    const int r    = lane >> 3;       // 0..7 tile row
    const int wcg  = lane & 7;        // 0..7 col group (8 w-pixels each)

    const int bid = blockIdx.x;
    const int b   = bid / 96;         // 24 h-tiles * 4 w-tiles = 96
    const int rem = bid % 96;
    const int th  = rem >> 2;
    const int tw  = rem & 3;
    const int h0  = th * TH;
    const int w0  = tw * TW;

    // ---------- staging descriptors (constant across chunks) ----------
    // x2 halo: 4ch x 16rows x 18 float4 = 1152 items; thread does q=tid, tid+576
    const int q0 = tid, q1 = tid + THREADS;
    const int ch_a = q0 / 288, ra = q0 % 288, hr_a = ra / 18, fc_a = ra % 18;
    const int ch_b = q1 / 288, rb = q1 % 288, hr_b = rb / 18, fc_b = rb % 18;
    const int hg_a = h0 + hr_a - 4, wg_a = w0 - 4 + fc_a * 4;
    const int hg_b = h0 + hr_b - 4, wg_b = w0 - 4 + fc_b * 4;
    const bool va = (hg_a >= 0 && hg_a < HH && wg_a >= 0 && wg_a < WW);
    const bool vb = (hg_b >= 0 && hg_b < HH && wg_b >= 0 && wg_b < WW);
    const int g2a = ((b * CC_ALL + ch_a) * HH + hg_a) * WW + wg_a;
    const int g2b = ((b * CC_ALL + ch_b) * HH + hg_b) * WW + wg_b;
    const int l2a = ch_a * ((TH + 8) * LDW2) + hr_a * LDW2 + fc_a * 4;
    const int l2b = ch_b * ((TH + 8) * LDW2) + hr_b * LDW2 + fc_b * 4;

    // x1 tile: 4ch x 8rows x 16 float4 = 512 items; threads 0..511
    const bool has1 = (tid < 512);
    const int ch1 = tid >> 7, r1i = tid & 127, hr1 = r1i >> 4, fc1 = r1i & 15;
    const int g1 = ((b * CC_ALL + ch1) * HH + (h0 + hr1)) * WW + w0 + fc1 * 4;
    const int l1 = ch1 * (TH * LDW1) + hr1 * LDW1 + fc1 * 4;

    const float4 z4 = make_float4(0.f, 0.f, 0.f, 0.f);
    float4 f2a = z4, f2b = z4, f1v = z4;

    auto load_chunk = [&](int n) {
        const int off = n * (CCH * HH * WW);
        f2a = va ? *(const float4*)(x2 + g2a + off) : z4;
        f2b = vb ? *(const float4*)(x2 + g2b + off) : z4;
        if (has1) f1v = *(const float4*)(x1 + g1 + off);
    };
    auto write_chunk = [&](int buf) {
        *(float4*)&s2[buf][l2a] = f2a;
        *(float4*)&s2[buf][l2b] = f2b;
        if (has1) *(float4*)&s1[buf][l1] = f1v;
    };

    float acc[9][8];
#pragma unroll
    for (int jj = 0; jj < 9; ++jj)
#pragma unroll
        for (int p = 0; p < 8; ++p) acc[jj][p] = 0.f;

    const int row2 = r + 8 - wave;   // = r + 4 - i, in [0,15]

    load_chunk(0);
    write_chunk(0);
    __syncthreads();

    for (int n = 0; n < NCHUNK; ++n) {
        if (n + 1 < NCHUNK) load_chunk(n + 1);
        const int cur = n & 1;
#pragma unroll
        for (int cc = 0; cc < CCH; ++cc) {
            const float* p1 = &s1[cur][cc * (TH * LDW1) + r * LDW1 + wcg * 8];
            const float4 a0 = *(const float4*)p1;
            const float4 a1 = *(const float4*)(p1 + 4);
            const float* p2 = &s2[cur][cc * ((TH + 8) * LDW2) + row2 * LDW2 + wcg * 8];
            const float4 b0 = *(const float4*)p2;
            const float4 b1 = *(const float4*)(p2 + 4);
            const float4 b2 = *(const float4*)(p2 + 8);
            const float4 b3 = *(const float4*)(p2 + 12);
            const float xv[16] = {b0.x, b0.y, b0.z, b0.w, b1.x, b1.y, b1.z, b1.w,
                                  b2.x, b2.y, b2.z, b2.w, b3.x, b3.y, b3.z, b3.w};
            const float av[8]  = {a0.x, a0.y, a0.z, a0.w, a1.x, a1.y, a1.z, a1.w};
            // out pixel w = w0 + wcg*8 + p needs x2 at w - j; xv[m] holds w0+wcg*8-4+m
            // j = jj-4  ->  m = p + 8 - jj  (in [0,15])
#pragma unroll
            for (int jj = 0; jj < 9; ++jj) {
#pragma unroll
                for (int p = 0; p < 8; ++p)
                    acc[jj][p] = fmaf(av[p], xv[p + 8 - jj], acc[jj][p]);
            }
        }
        __syncthreads();
        if (n + 1 < NCHUNK) write_chunk((n + 1) & 1);
        __syncthreads();
    }

    // ---------- epilogue: scale and store ----------
    const float scale = 1.0f / 81.0f;
    const int hout = h0 + r;
    const int wout = w0 + wcg * 8;
#pragma unroll
    for (int jj = 0; jj < 9; ++jj) {
        // k = (9*i + j) mod 81, i = wave-4, j = jj-4  ->  (9*wave + jj - 40) mod 81
        const int k = (9 * wave + jj + 41) % 81;
        float* po = out + ((b * 81 + k) * HH + hout) * WW + wout;
        vfloat4 o0 = {acc[jj][0] * scale, acc[jj][1] * scale,
                      acc[jj][2] * scale, acc[jj][3] * scale};
        vfloat4 o1 = {acc[jj][4] * scale, acc[jj][5] * scale,
                      acc[jj][6] * scale, acc[jj][7] * scale};
        __builtin_nontemporal_store(o0, (vfloat4*)po);
        __builtin_nontemporal_store(o1, (vfloat4*)(po + 4));
    }
}

extern "C" void kernel_launch(void* const* d_in, const int* in_sizes, int n_in,
                              void* d_out, int out_size, void* d_ws, size_t ws_size,
                              hipStream_t stream) {
    const float* x1 = (const float*)d_in[0];
    const float* x2 = (const float*)d_in[1];
    float* out = (float*)d_out;
    dim3 grid(BB * 24 * 4);   // 8 batches * 24 h-tiles * 4 w-tiles = 768
    dim3 block(THREADS);
    hipLaunchKernelGGL(cost_volume_kernel, grid, block, 0, stream, x1, x2, out);
}